// Round 14
// baseline (496.072 us; speedup 1.0000x reference)
//
#include <hip/hip_runtime.h>
#include <hip/hip_bf16.h>

#define N_NODES 100000
#define N_EDGES 3200000
#define HID 128
#define N_GRAPHS 512
#define N_CLASSES 10
#define NB 391            // ceil(N_NODES/256) buckets of 256 nodes
#define CAP 16128         // fixed bucket capacity (mean 8192 -> +87 sigma)
#define EPB 8192          // edges per block in bucket passes
#define NBLK_E 391        // ceil(N_EDGES/EPB)

typedef __attribute__((ext_vector_type(8))) short short8;
typedef __attribute__((ext_vector_type(4))) float floatx4;
typedef __attribute__((ext_vector_type(2))) float floatx2;

__device__ __forceinline__ unsigned short f2bf(float f) {
    union { float f; unsigned u; } x; x.f = f;
    unsigned r = x.u + 0x7fffu + ((x.u >> 16) & 1u);
    return (unsigned short)(r >> 16);
}
__device__ __forceinline__ float bf2f(unsigned short h) {
    union { unsigned u; float f; } x; x.u = ((unsigned)h) << 16;
    return x.f;
}

// ---------------- CSR build: fixed-capacity bucket sort ----------------
__global__ __launch_bounds__(256) void bucket_place_kernel(const int* __restrict__ src,
                                                           const int* __restrict__ dst,
                                                           int* __restrict__ bucket_fill,
                                                           unsigned* __restrict__ staged) {
    __shared__ int hist[NB];
    __shared__ int res[NB];
    for (int t = threadIdx.x; t < NB; t += 256) hist[t] = 0;
    __syncthreads();
    int base4 = blockIdx.x * (EPB / 4);
#pragma unroll 2
    for (int j = 0; j < 8; j++) {
        int idx4 = base4 + j * 256 + threadIdx.x;
        if (idx4 < N_EDGES / 4) {
            int4 d = ((const int4*)dst)[idx4];
            atomicAdd(&hist[d.x >> 8], 1);
            atomicAdd(&hist[d.y >> 8], 1);
            atomicAdd(&hist[d.z >> 8], 1);
            atomicAdd(&hist[d.w >> 8], 1);
        }
    }
    __syncthreads();
    for (int t = threadIdx.x; t < NB; t += 256) {
        int h = hist[t];
        res[t] = h ? atomicAdd(&bucket_fill[t], h) : 0;
        hist[t] = 0;   // reuse as local cursor
    }
    __syncthreads();
#pragma unroll 2
    for (int j = 0; j < 8; j++) {
        int idx4 = base4 + j * 256 + threadIdx.x;
        if (idx4 < N_EDGES / 4) {
            int4 d = ((const int4*)dst)[idx4];
            int4 s = ((const int4*)src)[idx4];
            int b, p;
            b = d.x >> 8; p = res[b] + atomicAdd(&hist[b], 1);
            staged[p] = ((unsigned)(d.x & 255) << 24) | (unsigned)s.x;
            b = d.y >> 8; p = res[b] + atomicAdd(&hist[b], 1);
            staged[p] = ((unsigned)(d.y & 255) << 24) | (unsigned)s.y;
            b = d.z >> 8; p = res[b] + atomicAdd(&hist[b], 1);
            staged[p] = ((unsigned)(d.z & 255) << 24) | (unsigned)s.z;
            b = d.w >> 8; p = res[b] + atomicAdd(&hist[b], 1);
            staged[p] = ((unsigned)(d.w & 255) << 24) | (unsigned)s.w;
        }
    }
}

__global__ void bucket_scan_kernel(const int* __restrict__ bucket_fill,
                                   int* __restrict__ bucket_base) {
    __shared__ int tmp[512];
    int tid = threadIdx.x;
    int v = (tid < NB) ? (bucket_fill[tid] - tid * CAP) : 0;
    tmp[tid] = v; __syncthreads();
    for (int off = 1; off < 512; off <<= 1) {
        int t = (tid >= off) ? tmp[tid - off] : 0;
        __syncthreads();
        tmp[tid] += t;
        __syncthreads();
    }
    if (tid < NB) bucket_base[tid] = tmp[tid] - v;
}

__global__ __launch_bounds__(256) void bucket_csr_kernel(const unsigned* __restrict__ staged,
                                                         const int* __restrict__ bucket_fill,
                                                         const int* __restrict__ bucket_base,
                                                         int* __restrict__ row_ptr,
                                                         int* __restrict__ csr) {
    __shared__ int deg[256];
    __shared__ int sc[256];
    __shared__ int fillc[256];
    int b = blockIdx.x, tid = threadIdx.x;
    int base = bucket_base[b];
    int cnt = bucket_fill[b] - b * CAP;
    int sbase = b * CAP;
    if (b == 0 && tid == 0) row_ptr[N_NODES] = N_EDGES;
    deg[tid] = 0; __syncthreads();
    for (int i = tid; i < cnt; i += 256) {
        unsigned e = staged[sbase + i];
        atomicAdd(&deg[e >> 24], 1);
    }
    __syncthreads();
    int v = deg[tid];
    sc[tid] = v; __syncthreads();
    for (int off = 1; off < 256; off <<= 1) {
        int t = (tid >= off) ? sc[tid - off] : 0;
        __syncthreads();
        sc[tid] += t;
        __syncthreads();
    }
    int excl = base + sc[tid] - v;
    int node = b * 256 + tid;
    if (node < N_NODES) row_ptr[node] = excl;
    fillc[tid] = excl;
    __syncthreads();
    for (int i = tid; i < cnt; i += 256) {
        unsigned e = staged[sbase + i];
        int p = atomicAdd(&fillc[e >> 24], 1);
        csr[p] = (int)(e & 0xFFFFFFu);
    }
}

// ---------------- dtype prep (x -> fp8 h8; weights; bucket_fill init) ----------------
__global__ void prep_kernel(const float* __restrict__ x, unsigned char* __restrict__ h8,
                            const float* __restrict__ W1, const float* __restrict__ W2,
                            unsigned short* __restrict__ w1t, unsigned short* __restrict__ w2t,
                            int* __restrict__ bucket_fill) {
    int i = blockIdx.x * 256 + threadIdx.x;
    if (i < NB) bucket_fill[i] = i * CAP;
    if (i < N_NODES * HID / 4) {
        const float4 v = *(const float4*)(x + (size_t)i * 4);
        int p = __builtin_amdgcn_cvt_pk_fp8_f32(v.x, v.y, 0, false);
        p = __builtin_amdgcn_cvt_pk_fp8_f32(v.z, v.w, p, true);
        *(unsigned*)(h8 + (size_t)i * 4) = (unsigned)p;
    } else {
        int idx = i - N_NODES * HID / 4;
        if (idx < 6 * 16384) {
            int m = idx / 16384;
            int r = idx & 16383;
            int n = r >> 7, k = r & 127;
            int l = m >> 1;
            if (m & 1) w2t[l * 16384 + n * 128 + k] = f2bf(W2[l * 16384 + k * 128 + n]);
            else       w1t[l * 16384 + n * 128 + k] = f2bf(W1[l * 16384 + k * 128 + n]);
        }
    }
}

// ---------------- per-layer aggregation: quad-packed fp8 gather ----------------
// 1 node/wave; 4 groups of 16 lanes. One vector csr load per 16 edges
// (lanes hold csr[i+l16]) + __shfl broadcast -> 5 VMEM instrs/iter (was 8).
// Packed floatx2 accumulators -> v_pk_add_f32 (16 adds/iter, was 32).
__global__ __launch_bounds__(256) void agg_kernel(const unsigned char* __restrict__ h8,
                                                  const int* __restrict__ row_ptr,
                                                  const int* __restrict__ csr,
                                                  const float* __restrict__ eps_p,
                                                  unsigned short* __restrict__ zb) {
    int wave = threadIdx.x >> 6;
    int node = blockIdx.x * 4 + wave;
    int L = threadIdx.x & 63;
    int g = L >> 4;
    int l16 = L & 15;
    int f8 = l16 * 8;                 // 8 feats per lane
    floatx2 c0 = {0.f, 0.f}, c1 = {0.f, 0.f}, c2 = {0.f, 0.f}, c3 = {0.f, 0.f};
    int beg = row_ptr[node], end = row_ptr[node + 1];
    int i = beg;
    for (; i + 16 <= end; i += 16) {
        int cval = csr[i + l16];      // 16 distinct dwords, shared across groups
#pragma unroll
        for (int j = 0; j < 4; j++) {
            int s = __shfl(cval, j * 4 + g);
            uint2 u = *(const uint2*)(h8 + (size_t)s * HID + f8);
            c0 += __builtin_amdgcn_cvt_pk_f32_fp8((int)u.x, false);
            c1 += __builtin_amdgcn_cvt_pk_f32_fp8((int)u.x, true);
            c2 += __builtin_amdgcn_cvt_pk_f32_fp8((int)u.y, false);
            c3 += __builtin_amdgcn_cvt_pk_f32_fp8((int)u.y, true);
        }
    }
    for (; i < end; i += 4) {
        int idx = i + g;
        uint2 u = {0u, 0u};
        if (idx < end) {
            int s = csr[idx];
            u = *(const uint2*)(h8 + (size_t)s * HID + f8);
        }
        c0 += __builtin_amdgcn_cvt_pk_f32_fp8((int)u.x, false);
        c1 += __builtin_amdgcn_cvt_pk_f32_fp8((int)u.x, true);
        c2 += __builtin_amdgcn_cvt_pk_f32_fp8((int)u.y, false);
        c3 += __builtin_amdgcn_cvt_pk_f32_fp8((int)u.y, true);
    }
    float a0 = c0.x, a1 = c0.y, a2 = c1.x, a3 = c1.y;
    float a4 = c2.x, a5 = c2.y, a6 = c3.x, a7 = c3.y;
    a0 += __shfl_xor(a0, 16); a1 += __shfl_xor(a1, 16);
    a2 += __shfl_xor(a2, 16); a3 += __shfl_xor(a3, 16);
    a4 += __shfl_xor(a4, 16); a5 += __shfl_xor(a5, 16);
    a6 += __shfl_xor(a6, 16); a7 += __shfl_xor(a7, 16);
    a0 += __shfl_xor(a0, 32); a1 += __shfl_xor(a1, 32);
    a2 += __shfl_xor(a2, 32); a3 += __shfl_xor(a3, 32);
    a4 += __shfl_xor(a4, 32); a5 += __shfl_xor(a5, 32);
    a6 += __shfl_xor(a6, 32); a7 += __shfl_xor(a7, 32);
    if (g == 0) {
        float epse = 1.0f + eps_p[0];
        uint2 hv = *(const uint2*)(h8 + (size_t)node * HID + f8);
        floatx2 q0 = __builtin_amdgcn_cvt_pk_f32_fp8((int)hv.x, false);
        floatx2 q1 = __builtin_amdgcn_cvt_pk_f32_fp8((int)hv.x, true);
        floatx2 q2 = __builtin_amdgcn_cvt_pk_f32_fp8((int)hv.y, false);
        floatx2 q3 = __builtin_amdgcn_cvt_pk_f32_fp8((int)hv.y, true);
        a0 += epse * q0.x; a1 += epse * q0.y;
        a2 += epse * q1.x; a3 += epse * q1.y;
        a4 += epse * q2.x; a5 += epse * q2.y;
        a6 += epse * q3.x; a7 += epse * q3.y;
        uint4 o;
        o.x = (unsigned)f2bf(a0) | ((unsigned)f2bf(a1) << 16);
        o.y = (unsigned)f2bf(a2) | ((unsigned)f2bf(a3) << 16);
        o.z = (unsigned)f2bf(a4) | ((unsigned)f2bf(a5) << 16);
        o.w = (unsigned)f2bf(a6) | ((unsigned)f2bf(a7) << 16);
        *(uint4*)(zb + (size_t)node * HID + f8) = o;
    }
}

// ---------------- fused MLP (64-row tile; stores h8 and/or bf16 h per flags) ----------------
__global__ __launch_bounds__(256) void mlp_kernel(const unsigned short* __restrict__ zb,
                                                  const unsigned short* __restrict__ w1t,
                                                  const float* __restrict__ b1,
                                                  const unsigned short* __restrict__ w2t,
                                                  const float* __restrict__ b2,
                                                  const float* __restrict__ gamma,
                                                  const float* __restrict__ beta,
                                                  const float* __restrict__ mu,
                                                  const float* __restrict__ var,
                                                  unsigned short* __restrict__ hb_out,
                                                  unsigned char* __restrict__ h8_out) {
    __shared__ __align__(16) unsigned short At[64][136];
    __shared__ __align__(16) unsigned short Wt[128][136];
    int tid = threadIdx.x;
    int row0 = blockIdx.x * 64;

    for (int c = tid; c < 1024; c += 256) {
        int r = c >> 4, cc = c & 15;
        int gr = row0 + r; if (gr >= N_NODES) gr = N_NODES - 1;
        *(uint4*)&At[r][cc * 8] = *(const uint4*)(zb + (size_t)gr * HID + cc * 8);
    }
    for (int c = tid; c < 2048; c += 256) {
        int r = c >> 4, cc = c & 15;
        *(uint4*)&Wt[r][cc * 8] = *(const uint4*)(w1t + r * 128 + cc * 8);
    }
    __syncthreads();

    int wave = tid >> 6, L = tid & 63, quad = L >> 4, l16 = L & 15;
    floatx4 acc[8];

#pragma unroll
    for (int t = 0; t < 8; t++) acc[t] = (floatx4){0.f, 0.f, 0.f, 0.f};
#pragma unroll
    for (int ks = 0; ks < 4; ks++) {
        short8 a = *(const short8*)&At[wave * 16 + l16][ks * 32 + quad * 8];
#pragma unroll
        for (int t = 0; t < 8; t++) {
            short8 b = *(const short8*)&Wt[t * 16 + l16][ks * 32 + quad * 8];
            acc[t] = __builtin_amdgcn_mfma_f32_16x16x32_bf16(a, b, acc[t], 0, 0, 0);
        }
    }
#pragma unroll
    for (int t = 0; t < 8; t++) {
        int col = t * 16 + l16;
        float bias = b1[col];
#pragma unroll
        for (int r = 0; r < 4; r++) {
            float v = acc[t][r] + bias;
            v = v > 0.f ? v : 0.f;
            At[wave * 16 + quad * 4 + r][col] = f2bf(v);
        }
    }
    __syncthreads();
    for (int c = tid; c < 2048; c += 256) {
        int r = c >> 4, cc = c & 15;
        *(uint4*)&Wt[r][cc * 8] = *(const uint4*)(w2t + r * 128 + cc * 8);
    }
    __syncthreads();

#pragma unroll
    for (int t = 0; t < 8; t++) acc[t] = (floatx4){0.f, 0.f, 0.f, 0.f};
#pragma unroll
    for (int ks = 0; ks < 4; ks++) {
        short8 a = *(const short8*)&At[wave * 16 + l16][ks * 32 + quad * 8];
#pragma unroll
        for (int t = 0; t < 8; t++) {
            short8 b = *(const short8*)&Wt[t * 16 + l16][ks * 32 + quad * 8];
            acc[t] = __builtin_amdgcn_mfma_f32_16x16x32_bf16(a, b, acc[t], 0, 0, 0);
        }
    }
    __syncthreads();
#pragma unroll
    for (int t = 0; t < 8; t++) {
        int col = t * 16 + l16;
        float bias = b2[col];
        float scale = gamma[col] * rsqrtf(var[col] + 1e-5f);
        float shift = beta[col] - mu[col] * scale;
#pragma unroll
        for (int r = 0; r < 4; r++) {
            float v = acc[t][r] + bias;
            v = v > 0.f ? v : 0.f;
            v = v * scale + shift;
            At[wave * 16 + quad * 4 + r][col] = f2bf(v);
        }
    }
    __syncthreads();
    for (int c = tid; c < 1024; c += 256) {
        int r = c >> 4, cc = c & 15;
        int gr = row0 + r;
        if (gr < N_NODES) {
            uint4 u = *(const uint4*)&At[r][cc * 8];
            if (hb_out) *(uint4*)(hb_out + (size_t)gr * HID + cc * 8) = u;
            if (h8_out) {
                float f0 = bf2f((unsigned short)(u.x & 0xffff)), f1 = bf2f((unsigned short)(u.x >> 16));
                float f2 = bf2f((unsigned short)(u.y & 0xffff)), f3 = bf2f((unsigned short)(u.y >> 16));
                float f4 = bf2f((unsigned short)(u.z & 0xffff)), f5 = bf2f((unsigned short)(u.z >> 16));
                float f6 = bf2f((unsigned short)(u.w & 0xffff)), f7 = bf2f((unsigned short)(u.w >> 16));
                int p0 = __builtin_amdgcn_cvt_pk_fp8_f32(f0, f1, 0, false);
                p0 = __builtin_amdgcn_cvt_pk_fp8_f32(f2, f3, p0, true);
                int p1 = __builtin_amdgcn_cvt_pk_fp8_f32(f4, f5, 0, false);
                p1 = __builtin_amdgcn_cvt_pk_fp8_f32(f6, f7, p1, true);
                uint2 o; o.x = (unsigned)p0; o.y = (unsigned)p1;
                *(uint2*)(h8_out + (size_t)gr * HID + cc * 8) = o;
            }
        }
    }
}

// ---------------- pooling + classifier head (16 rows in flight) ----------------
__global__ __launch_bounds__(256) void head_kernel(const unsigned short* __restrict__ hb,
                                                   const int* __restrict__ batch,
                                                   const float* __restrict__ l1w,
                                                   const float* __restrict__ l1b,
                                                   const float* __restrict__ l2w,
                                                   const float* __restrict__ l2b,
                                                   float* __restrict__ out) {
    int g = blockIdx.x, tid = threadIdx.x;
    __shared__ int s_lo, s_hi;
    if (tid == 0) {
        int lo = 0, hi = N_NODES;
        while (lo < hi) { int m = (lo + hi) >> 1; if (batch[m] < g) lo = m + 1; else hi = m; }
        s_lo = lo;
    }
    if (tid == 1) {
        int lo = 0, hi = N_NODES;
        int key = g + 1;
        while (lo < hi) { int m = (lo + hi) >> 1; if (batch[m] < key) lo = m + 1; else hi = m; }
        s_hi = lo;
    }
    __syncthreads();
    int lo = s_lo, hi = s_hi;
    int rg = tid >> 6, L = tid & 63, f = L * 2;
    float a0 = 0.f, a1 = 0.f;
    int n = lo + rg;
    for (; n + 16 <= hi; n += 16) {
        ushort2 v0 = *(const ushort2*)(hb + (size_t)n * HID + f);
        ushort2 v1 = *(const ushort2*)(hb + (size_t)(n + 4) * HID + f);
        ushort2 v2 = *(const ushort2*)(hb + (size_t)(n + 8) * HID + f);
        ushort2 v3 = *(const ushort2*)(hb + (size_t)(n + 12) * HID + f);
        a0 += bf2f(v0.x) + bf2f(v1.x) + bf2f(v2.x) + bf2f(v3.x);
        a1 += bf2f(v0.y) + bf2f(v1.y) + bf2f(v2.y) + bf2f(v3.y);
    }
    for (; n < hi; n += 4) {
        ushort2 v = *(const ushort2*)(hb + (size_t)n * HID + f);
        a0 += bf2f(v.x);
        a1 += bf2f(v.y);
    }
    __shared__ float red[4][128];
    red[rg][f] = a0; red[rg][f + 1] = a1;
    __syncthreads();
    float cnt = (float)(hi - lo);
    if (cnt < 1.f) cnt = 1.f;
    __shared__ float sp[128];
    if (tid < 128) sp[tid] = (red[0][tid] + red[1][tid] + red[2][tid] + red[3][tid]) / cnt;
    __syncthreads();
    __shared__ float so[128];
    if (tid < 128) {
        float o1 = l1b[tid];
        for (int k = 0; k < 128; k++) o1 += sp[k] * l1w[k * 128 + tid];
        so[tid] = fmaxf(o1, 0.f);
    }
    __syncthreads();
    __shared__ float s2[N_CLASSES];
    if (tid < N_CLASSES) {
        float o2 = l2b[tid];
        for (int k = 0; k < 128; k++) o2 += so[k] * l2w[k * N_CLASSES + tid];
        s2[tid] = o2;
    }
    __syncthreads();
    __shared__ float sm[2];
    if (tid == 0) {
        float m = s2[0];
        for (int c = 1; c < N_CLASSES; c++) m = fmaxf(m, s2[c]);
        float s = 0.f;
        for (int c = 0; c < N_CLASSES; c++) s += expf(s2[c] - m);
        sm[0] = m; sm[1] = logf(s);
    }
    __syncthreads();
    if (tid < N_CLASSES) out[g * N_CLASSES + tid] = s2[tid] - sm[0] - sm[1];
}

extern "C" void kernel_launch(void* const* d_in, const int* in_sizes, int n_in,
                              void* d_out, int out_size, void* d_ws, size_t ws_size,
                              hipStream_t stream) {
    (void)in_sizes; (void)n_in; (void)out_size; (void)ws_size;
    const float* x     = (const float*)d_in[0];
    const int*   ei    = (const int*)d_in[1];
    const int*   batch = (const int*)d_in[2];
    const float* W1    = (const float*)d_in[3];
    const float* b1    = (const float*)d_in[4];
    const float* W2    = (const float*)d_in[5];
    const float* b2    = (const float*)d_in[6];
    const float* gamma = (const float*)d_in[7];
    const float* beta  = (const float*)d_in[8];
    const float* mu    = (const float*)d_in[9];
    const float* var   = (const float*)d_in[10];
    const float* eps   = (const float*)d_in[11];
    const float* l1w   = (const float*)d_in[12];
    const float* l1b   = (const float*)d_in[13];
    const float* l2w   = (const float*)d_in[14];
    const float* l2b   = (const float*)d_in[15];
    float* out = (float*)d_out;

    char* ws = (char*)d_ws;
    size_t off = 0;
    auto alloc = [&](size_t bytes) -> void* {
        void* p = ws + off;
        off += (bytes + 255) & ~(size_t)255;
        return p;
    };
    int* bucket_fill  = (int*)alloc((size_t)NB * 4);
    int* bucket_base  = (int*)alloc((size_t)NB * 4);
    int* row_ptr      = (int*)alloc((size_t)(N_NODES + 1) * 4);
    int* csr          = (int*)alloc((size_t)N_EDGES * 4);
    unsigned short* hb1 = (unsigned short*)alloc((size_t)N_NODES * HID * 2);
    unsigned short* zb  = (unsigned short*)alloc((size_t)N_NODES * HID * 2);
    unsigned char*  h8  = (unsigned char*)alloc((size_t)N_NODES * HID);
    unsigned short* w1t = (unsigned short*)alloc(3 * 128 * 128 * 2);
    unsigned short* w2t = (unsigned short*)alloc(3 * 128 * 128 * 2);

    // staged (NB*CAP*4 = 25.22 MB) aliases hb1 (25.6 MB): hb1 is first written
    // by layer-2 mlp, long after bucket_csr consumes staged.
    unsigned* staged = (unsigned*)hb1;

    const int* srcA = ei;
    const int* dstA = ei + N_EDGES;

    // prep first: also initializes bucket_fill for the CSR build
    prep_kernel<<<(N_NODES * HID / 4 + 6 * 16384 + 255) / 256, 256, 0, stream>>>(
        x, h8, W1, W2, w1t, w2t, bucket_fill);
    bucket_place_kernel<<<NBLK_E, 256, 0, stream>>>(srcA, dstA, bucket_fill, staged);
    bucket_scan_kernel<<<1, 512, 0, stream>>>(bucket_fill, bucket_base);
    bucket_csr_kernel<<<NB, 256, 0, stream>>>(staged, bucket_fill, bucket_base, row_ptr, csr);

    for (int l = 0; l < 3; l++) {
        agg_kernel<<<N_NODES / 4, 256, 0, stream>>>(h8, row_ptr, csr, eps + l, zb);
        mlp_kernel<<<(N_NODES + 63) / 64, 256, 0, stream>>>(
            zb, w1t + l * 16384, b1 + l * 128, w2t + l * 16384, b2 + l * 128,
            gamma + l * 128, beta + l * 128, mu + l * 128, var + l * 128,
            (l == 2) ? hb1 : (unsigned short*)nullptr,
            (l == 2) ? (unsigned char*)nullptr : h8);
    }
    head_kernel<<<N_GRAPHS, 256, 0, stream>>>(hb1, batch, l1w, l1b, l2w, l2b, out);
}

// Round 18
// 492.982 us; speedup vs baseline: 1.0063x; 1.0063x over previous
//
#include <hip/hip_runtime.h>
#include <hip/hip_bf16.h>

#define N_NODES 100000
#define N_EDGES 3200000
#define HID 128
#define N_GRAPHS 512
#define N_CLASSES 10
#define NB 391            // ceil(N_NODES/256) buckets of 256 nodes
#define CAP 16128         // fixed bucket capacity (mean 8192 -> +87 sigma)
#define EPB 8192          // edges per block in bucket passes
#define NBLK_E 391        // ceil(N_EDGES/EPB)
#define ZSCALE 0.0625f    // store z/16 in fp8 (avoid e4m3 448-clamp bias)
#define ZUNSCALE 16.0f

typedef __attribute__((ext_vector_type(8))) short short8;
typedef __attribute__((ext_vector_type(4))) float floatx4;
typedef __attribute__((ext_vector_type(2))) float floatx2;

__device__ __forceinline__ unsigned short f2bf(float f) {
    union { float f; unsigned u; } x; x.f = f;
    unsigned r = x.u + 0x7fffu + ((x.u >> 16) & 1u);
    return (unsigned short)(r >> 16);
}
__device__ __forceinline__ float bf2f(unsigned short h) {
    union { unsigned u; float f; } x; x.u = ((unsigned)h) << 16;
    return x.f;
}

// ---------------- CSR build: fixed-capacity bucket sort ----------------
__global__ __launch_bounds__(256) void bucket_place_kernel(const int* __restrict__ src,
                                                           const int* __restrict__ dst,
                                                           int* __restrict__ bucket_fill,
                                                           unsigned* __restrict__ staged) {
    __shared__ int hist[NB];
    __shared__ int res[NB];
    for (int t = threadIdx.x; t < NB; t += 256) hist[t] = 0;
    __syncthreads();
    int base4 = blockIdx.x * (EPB / 4);
#pragma unroll 2
    for (int j = 0; j < 8; j++) {
        int idx4 = base4 + j * 256 + threadIdx.x;
        if (idx4 < N_EDGES / 4) {
            int4 d = ((const int4*)dst)[idx4];
            atomicAdd(&hist[d.x >> 8], 1);
            atomicAdd(&hist[d.y >> 8], 1);
            atomicAdd(&hist[d.z >> 8], 1);
            atomicAdd(&hist[d.w >> 8], 1);
        }
    }
    __syncthreads();
    for (int t = threadIdx.x; t < NB; t += 256) {
        int h = hist[t];
        res[t] = h ? atomicAdd(&bucket_fill[t], h) : 0;
        hist[t] = 0;   // reuse as local cursor
    }
    __syncthreads();
#pragma unroll 2
    for (int j = 0; j < 8; j++) {
        int idx4 = base4 + j * 256 + threadIdx.x;
        if (idx4 < N_EDGES / 4) {
            int4 d = ((const int4*)dst)[idx4];
            int4 s = ((const int4*)src)[idx4];
            int b, p;
            b = d.x >> 8; p = res[b] + atomicAdd(&hist[b], 1);
            staged[p] = ((unsigned)(d.x & 255) << 24) | (unsigned)s.x;
            b = d.y >> 8; p = res[b] + atomicAdd(&hist[b], 1);
            staged[p] = ((unsigned)(d.y & 255) << 24) | (unsigned)s.y;
            b = d.z >> 8; p = res[b] + atomicAdd(&hist[b], 1);
            staged[p] = ((unsigned)(d.z & 255) << 24) | (unsigned)s.z;
            b = d.w >> 8; p = res[b] + atomicAdd(&hist[b], 1);
            staged[p] = ((unsigned)(d.w & 255) << 24) | (unsigned)s.w;
        }
    }
}

__global__ void bucket_scan_kernel(const int* __restrict__ bucket_fill,
                                   int* __restrict__ bucket_base) {
    __shared__ int tmp[512];
    int tid = threadIdx.x;
    int v = (tid < NB) ? (bucket_fill[tid] - tid * CAP) : 0;
    tmp[tid] = v; __syncthreads();
    for (int off = 1; off < 512; off <<= 1) {
        int t = (tid >= off) ? tmp[tid - off] : 0;
        __syncthreads();
        tmp[tid] += t;
        __syncthreads();
    }
    if (tid < NB) bucket_base[tid] = tmp[tid] - v;
}

__global__ __launch_bounds__(256) void bucket_csr_kernel(const unsigned* __restrict__ staged,
                                                         const int* __restrict__ bucket_fill,
                                                         const int* __restrict__ bucket_base,
                                                         int* __restrict__ row_ptr,
                                                         int* __restrict__ csr) {
    __shared__ int deg[256];
    __shared__ int sc[256];
    __shared__ int fillc[256];
    int b = blockIdx.x, tid = threadIdx.x;
    int base = bucket_base[b];
    int cnt = bucket_fill[b] - b * CAP;
    int sbase = b * CAP;
    if (b == 0 && tid == 0) row_ptr[N_NODES] = N_EDGES;
    deg[tid] = 0; __syncthreads();
    for (int i = tid; i < cnt; i += 256) {
        unsigned e = staged[sbase + i];
        atomicAdd(&deg[e >> 24], 1);
    }
    __syncthreads();
    int v = deg[tid];
    sc[tid] = v; __syncthreads();
    for (int off = 1; off < 256; off <<= 1) {
        int t = (tid >= off) ? sc[tid - off] : 0;
        __syncthreads();
        sc[tid] += t;
        __syncthreads();
    }
    int excl = base + sc[tid] - v;
    int node = b * 256 + tid;
    if (node < N_NODES) row_ptr[node] = excl;
    fillc[tid] = excl;
    __syncthreads();
    for (int i = tid; i < cnt; i += 256) {
        unsigned e = staged[sbase + i];
        int p = atomicAdd(&fillc[e >> 24], 1);
        csr[p] = (int)(e & 0xFFFFFFu);
    }
}

// ---------------- dtype prep (x -> fp8 h8; weights bf16; bucket_fill init) ----------------
__global__ void prep_kernel(const float* __restrict__ x, unsigned char* __restrict__ h8,
                            const float* __restrict__ W1, const float* __restrict__ W2,
                            unsigned short* __restrict__ w1t, unsigned short* __restrict__ w2t,
                            int* __restrict__ bucket_fill) {
    int i = blockIdx.x * 256 + threadIdx.x;
    if (i < NB) bucket_fill[i] = i * CAP;
    if (i < N_NODES * HID / 4) {
        const float4 v = *(const float4*)(x + (size_t)i * 4);
        int p = __builtin_amdgcn_cvt_pk_fp8_f32(v.x, v.y, 0, false);
        p = __builtin_amdgcn_cvt_pk_fp8_f32(v.z, v.w, p, true);
        *(unsigned*)(h8 + (size_t)i * 4) = (unsigned)p;
    } else {
        int idx = i - N_NODES * HID / 4;
        if (idx < 6 * 16384) {
            int m = idx / 16384;
            int r = idx & 16383;
            int n = r >> 7, k = r & 127;
            int l = m >> 1;
            if (m & 1) w2t[l * 16384 + n * 128 + k] = f2bf(W2[l * 16384 + k * 128 + n]);
            else       w1t[l * 16384 + n * 128 + k] = f2bf(W1[l * 16384 + k * 128 + n]);
        }
    }
}

// ---------------- per-layer aggregation: quad-packed fp8 gather, scaled fp8 z out ----------------
__global__ __launch_bounds__(256) void agg_kernel(const unsigned char* __restrict__ h8,
                                                  const int* __restrict__ row_ptr,
                                                  const int* __restrict__ csr,
                                                  const float* __restrict__ eps_p,
                                                  unsigned char* __restrict__ zb8) {
    int wave = threadIdx.x >> 6;
    int node = blockIdx.x * 4 + wave;
    int L = threadIdx.x & 63;
    int g = L >> 4;
    int l16 = L & 15;
    int f8 = l16 * 8;                 // 8 feats per lane
    floatx2 c0 = {0.f, 0.f}, c1 = {0.f, 0.f}, c2 = {0.f, 0.f}, c3 = {0.f, 0.f};
    int beg = row_ptr[node], end = row_ptr[node + 1];
    int i = beg;
    for (; i + 16 <= end; i += 16) {
        int cval = csr[i + l16];      // 16 distinct dwords, shared across groups
#pragma unroll
        for (int j = 0; j < 4; j++) {
            int s = __shfl(cval, j * 4 + g);
            uint2 u = *(const uint2*)(h8 + (size_t)s * HID + f8);
            c0 += __builtin_amdgcn_cvt_pk_f32_fp8((int)u.x, false);
            c1 += __builtin_amdgcn_cvt_pk_f32_fp8((int)u.x, true);
            c2 += __builtin_amdgcn_cvt_pk_f32_fp8((int)u.y, false);
            c3 += __builtin_amdgcn_cvt_pk_f32_fp8((int)u.y, true);
        }
    }
    for (; i < end; i += 4) {
        int idx = i + g;
        uint2 u = {0u, 0u};
        if (idx < end) {
            int s = csr[idx];
            u = *(const uint2*)(h8 + (size_t)s * HID + f8);
        }
        c0 += __builtin_amdgcn_cvt_pk_f32_fp8((int)u.x, false);
        c1 += __builtin_amdgcn_cvt_pk_f32_fp8((int)u.x, true);
        c2 += __builtin_amdgcn_cvt_pk_f32_fp8((int)u.y, false);
        c3 += __builtin_amdgcn_cvt_pk_f32_fp8((int)u.y, true);
    }
    float a0 = c0.x, a1 = c0.y, a2 = c1.x, a3 = c1.y;
    float a4 = c2.x, a5 = c2.y, a6 = c3.x, a7 = c3.y;
    a0 += __shfl_xor(a0, 16); a1 += __shfl_xor(a1, 16);
    a2 += __shfl_xor(a2, 16); a3 += __shfl_xor(a3, 16);
    a4 += __shfl_xor(a4, 16); a5 += __shfl_xor(a5, 16);
    a6 += __shfl_xor(a6, 16); a7 += __shfl_xor(a7, 16);
    a0 += __shfl_xor(a0, 32); a1 += __shfl_xor(a1, 32);
    a2 += __shfl_xor(a2, 32); a3 += __shfl_xor(a3, 32);
    a4 += __shfl_xor(a4, 32); a5 += __shfl_xor(a5, 32);
    a6 += __shfl_xor(a6, 32); a7 += __shfl_xor(a7, 32);
    if (g == 0) {
        float epse = 1.0f + eps_p[0];
        uint2 hv = *(const uint2*)(h8 + (size_t)node * HID + f8);
        floatx2 q0 = __builtin_amdgcn_cvt_pk_f32_fp8((int)hv.x, false);
        floatx2 q1 = __builtin_amdgcn_cvt_pk_f32_fp8((int)hv.x, true);
        floatx2 q2 = __builtin_amdgcn_cvt_pk_f32_fp8((int)hv.y, false);
        floatx2 q3 = __builtin_amdgcn_cvt_pk_f32_fp8((int)hv.y, true);
        a0 += epse * q0.x; a1 += epse * q0.y;
        a2 += epse * q1.x; a3 += epse * q1.y;
        a4 += epse * q2.x; a5 += epse * q2.y;
        a6 += epse * q3.x; a7 += epse * q3.y;
        // store z/16: keeps tail features far below the e4m3 448-clamp (bias-free)
        a0 *= ZSCALE; a1 *= ZSCALE; a2 *= ZSCALE; a3 *= ZSCALE;
        a4 *= ZSCALE; a5 *= ZSCALE; a6 *= ZSCALE; a7 *= ZSCALE;
        int p0 = __builtin_amdgcn_cvt_pk_fp8_f32(a0, a1, 0, false);
        p0 = __builtin_amdgcn_cvt_pk_fp8_f32(a2, a3, p0, true);
        int p1 = __builtin_amdgcn_cvt_pk_fp8_f32(a4, a5, 0, false);
        p1 = __builtin_amdgcn_cvt_pk_fp8_f32(a6, a7, p1, true);
        uint2 o; o.x = (unsigned)p0; o.y = (unsigned)p1;
        *(uint2*)(zb8 + (size_t)node * HID + f8) = o;
    }
}

// ---------------- fused MLP: bf16 MFMA (verified), A staged from scaled fp8 z ----------------
__global__ __launch_bounds__(256) void mlp_kernel(const unsigned char* __restrict__ zb8,
                                                  const unsigned short* __restrict__ w1t,
                                                  const float* __restrict__ b1,
                                                  const unsigned short* __restrict__ w2t,
                                                  const float* __restrict__ b2,
                                                  const float* __restrict__ gamma,
                                                  const float* __restrict__ beta,
                                                  const float* __restrict__ mu,
                                                  const float* __restrict__ var,
                                                  unsigned short* __restrict__ hb_out,
                                                  unsigned char* __restrict__ h8_out) {
    __shared__ __align__(16) unsigned short At[64][136];
    __shared__ __align__(16) unsigned short Wt[128][136];
    int tid = threadIdx.x;
    int row0 = blockIdx.x * 64;

    // stage A: 64 x 128 scaled-fp8 -> bf16, x16 restore (exact pow2 scaling)
    for (int c = tid; c < 1024; c += 256) {
        int r = c >> 4, cc = c & 15;
        int gr = row0 + r; if (gr >= N_NODES) gr = N_NODES - 1;
        uint2 u = *(const uint2*)(zb8 + (size_t)gr * HID + cc * 8);
        floatx2 p0 = __builtin_amdgcn_cvt_pk_f32_fp8((int)u.x, false);
        floatx2 p1 = __builtin_amdgcn_cvt_pk_f32_fp8((int)u.x, true);
        floatx2 p2 = __builtin_amdgcn_cvt_pk_f32_fp8((int)u.y, false);
        floatx2 p3 = __builtin_amdgcn_cvt_pk_f32_fp8((int)u.y, true);
        uint4 o;
        o.x = (unsigned)f2bf(p0.x * ZUNSCALE) | ((unsigned)f2bf(p0.y * ZUNSCALE) << 16);
        o.y = (unsigned)f2bf(p1.x * ZUNSCALE) | ((unsigned)f2bf(p1.y * ZUNSCALE) << 16);
        o.z = (unsigned)f2bf(p2.x * ZUNSCALE) | ((unsigned)f2bf(p2.y * ZUNSCALE) << 16);
        o.w = (unsigned)f2bf(p3.x * ZUNSCALE) | ((unsigned)f2bf(p3.y * ZUNSCALE) << 16);
        *(uint4*)&At[r][cc * 8] = o;
    }
    for (int c = tid; c < 2048; c += 256) {
        int r = c >> 4, cc = c & 15;
        *(uint4*)&Wt[r][cc * 8] = *(const uint4*)(w1t + r * 128 + cc * 8);
    }
    __syncthreads();

    int wave = tid >> 6, L = tid & 63, quad = L >> 4, l16 = L & 15;
    floatx4 acc[8];

#pragma unroll
    for (int t = 0; t < 8; t++) acc[t] = (floatx4){0.f, 0.f, 0.f, 0.f};
#pragma unroll
    for (int ks = 0; ks < 4; ks++) {
        short8 a = *(const short8*)&At[wave * 16 + l16][ks * 32 + quad * 8];
#pragma unroll
        for (int t = 0; t < 8; t++) {
            short8 b = *(const short8*)&Wt[t * 16 + l16][ks * 32 + quad * 8];
            acc[t] = __builtin_amdgcn_mfma_f32_16x16x32_bf16(a, b, acc[t], 0, 0, 0);
        }
    }
#pragma unroll
    for (int t = 0; t < 8; t++) {
        int col = t * 16 + l16;
        float bias = b1[col];
#pragma unroll
        for (int r = 0; r < 4; r++) {
            float v = acc[t][r] + bias;
            v = v > 0.f ? v : 0.f;
            At[wave * 16 + quad * 4 + r][col] = f2bf(v);
        }
    }
    __syncthreads();
    for (int c = tid; c < 2048; c += 256) {
        int r = c >> 4, cc = c & 15;
        *(uint4*)&Wt[r][cc * 8] = *(const uint4*)(w2t + r * 128 + cc * 8);
    }
    __syncthreads();

#pragma unroll
    for (int t = 0; t < 8; t++) acc[t] = (floatx4){0.f, 0.f, 0.f, 0.f};
#pragma unroll
    for (int ks = 0; ks < 4; ks++) {
        short8 a = *(const short8*)&At[wave * 16 + l16][ks * 32 + quad * 8];
#pragma unroll
        for (int t = 0; t < 8; t++) {
            short8 b = *(const short8*)&Wt[t * 16 + l16][ks * 32 + quad * 8];
            acc[t] = __builtin_amdgcn_mfma_f32_16x16x32_bf16(a, b, acc[t], 0, 0, 0);
        }
    }
    __syncthreads();
#pragma unroll
    for (int t = 0; t < 8; t++) {
        int col = t * 16 + l16;
        float bias = b2[col];
        float scale = gamma[col] * rsqrtf(var[col] + 1e-5f);
        float shift = beta[col] - mu[col] * scale;
#pragma unroll
        for (int r = 0; r < 4; r++) {
            float v = acc[t][r] + bias;
            v = v > 0.f ? v : 0.f;
            v = v * scale + shift;
            At[wave * 16 + quad * 4 + r][col] = f2bf(v);
        }
    }
    __syncthreads();
    for (int c = tid; c < 1024; c += 256) {
        int r = c >> 4, cc = c & 15;
        int gr = row0 + r;
        if (gr < N_NODES) {
            uint4 u = *(const uint4*)&At[r][cc * 8];
            if (hb_out) *(uint4*)(hb_out + (size_t)gr * HID + cc * 8) = u;
            if (h8_out) {
                float f0 = bf2f((unsigned short)(u.x & 0xffff)), f1 = bf2f((unsigned short)(u.x >> 16));
                float f2 = bf2f((unsigned short)(u.y & 0xffff)), f3 = bf2f((unsigned short)(u.y >> 16));
                float f4 = bf2f((unsigned short)(u.z & 0xffff)), f5 = bf2f((unsigned short)(u.z >> 16));
                float f6 = bf2f((unsigned short)(u.w & 0xffff)), f7 = bf2f((unsigned short)(u.w >> 16));
                int p0 = __builtin_amdgcn_cvt_pk_fp8_f32(f0, f1, 0, false);
                p0 = __builtin_amdgcn_cvt_pk_fp8_f32(f2, f3, p0, true);
                int p1 = __builtin_amdgcn_cvt_pk_fp8_f32(f4, f5, 0, false);
                p1 = __builtin_amdgcn_cvt_pk_fp8_f32(f6, f7, p1, true);
                uint2 o; o.x = (unsigned)p0; o.y = (unsigned)p1;
                *(uint2*)(h8_out + (size_t)gr * HID + cc * 8) = o;
            }
        }
    }
}

// ---------------- pooling + classifier head (16 rows in flight) ----------------
__global__ __launch_bounds__(256) void head_kernel(const unsigned short* __restrict__ hb,
                                                   const int* __restrict__ batch,
                                                   const float* __restrict__ l1w,
                                                   const float* __restrict__ l1b,
                                                   const float* __restrict__ l2w,
                                                   const float* __restrict__ l2b,
                                                   float* __restrict__ out) {
    int g = blockIdx.x, tid = threadIdx.x;
    __shared__ int s_lo, s_hi;
    if (tid == 0) {
        int lo = 0, hi = N_NODES;
        while (lo < hi) { int m = (lo + hi) >> 1; if (batch[m] < g) lo = m + 1; else hi = m; }
        s_lo = lo;
    }
    if (tid == 1) {
        int lo = 0, hi = N_NODES;
        int key = g + 1;
        while (lo < hi) { int m = (lo + hi) >> 1; if (batch[m] < key) lo = m + 1; else hi = m; }
        s_hi = lo;
    }
    __syncthreads();
    int lo = s_lo, hi = s_hi;
    int rg = tid >> 6, L = tid & 63, f = L * 2;
    float a0 = 0.f, a1 = 0.f;
    int n = lo + rg;
    for (; n + 16 <= hi; n += 16) {
        ushort2 v0 = *(const ushort2*)(hb + (size_t)n * HID + f);
        ushort2 v1 = *(const ushort2*)(hb + (size_t)(n + 4) * HID + f);
        ushort2 v2 = *(const ushort2*)(hb + (size_t)(n + 8) * HID + f);
        ushort2 v3 = *(const ushort2*)(hb + (size_t)(n + 12) * HID + f);
        a0 += bf2f(v0.x) + bf2f(v1.x) + bf2f(v2.x) + bf2f(v3.x);
        a1 += bf2f(v0.y) + bf2f(v1.y) + bf2f(v2.y) + bf2f(v3.y);
    }
    for (; n < hi; n += 4) {
        ushort2 v = *(const ushort2*)(hb + (size_t)n * HID + f);
        a0 += bf2f(v.x);
        a1 += bf2f(v.y);
    }
    __shared__ float red[4][128];
    red[rg][f] = a0; red[rg][f + 1] = a1;
    __syncthreads();
    float cnt = (float)(hi - lo);
    if (cnt < 1.f) cnt = 1.f;
    __shared__ float sp[128];
    if (tid < 128) sp[tid] = (red[0][tid] + red[1][tid] + red[2][tid] + red[3][tid]) / cnt;
    __syncthreads();
    __shared__ float so[128];
    if (tid < 128) {
        float o1 = l1b[tid];
        for (int k = 0; k < 128; k++) o1 += sp[k] * l1w[k * 128 + tid];
        so[tid] = fmaxf(o1, 0.f);
    }
    __syncthreads();
    __shared__ float s2[N_CLASSES];
    if (tid < N_CLASSES) {
        float o2 = l2b[tid];
        for (int k = 0; k < 128; k++) o2 += so[k] * l2w[k * N_CLASSES + tid];
        s2[tid] = o2;
    }
    __syncthreads();
    __shared__ float sm[2];
    if (tid == 0) {
        float m = s2[0];
        for (int c = 1; c < N_CLASSES; c++) m = fmaxf(m, s2[c]);
        float s = 0.f;
        for (int c = 0; c < N_CLASSES; c++) s += expf(s2[c] - m);
        sm[0] = m; sm[1] = logf(s);
    }
    __syncthreads();
    if (tid < N_CLASSES) out[g * N_CLASSES + tid] = s2[tid] - sm[0] - sm[1];
}

extern "C" void kernel_launch(void* const* d_in, const int* in_sizes, int n_in,
                              void* d_out, int out_size, void* d_ws, size_t ws_size,
                              hipStream_t stream) {
    (void)in_sizes; (void)n_in; (void)out_size; (void)ws_size;
    const float* x     = (const float*)d_in[0];
    const int*   ei    = (const int*)d_in[1];
    const int*   batch = (const int*)d_in[2];
    const float* W1    = (const float*)d_in[3];
    const float* b1    = (const float*)d_in[4];
    const float* W2    = (const float*)d_in[5];
    const float* b2    = (const float*)d_in[6];
    const float* gamma = (const float*)d_in[7];
    const float* beta  = (const float*)d_in[8];
    const float* mu    = (const float*)d_in[9];
    const float* var   = (const float*)d_in[10];
    const float* eps   = (const float*)d_in[11];
    const float* l1w   = (const float*)d_in[12];
    const float* l1b   = (const float*)d_in[13];
    const float* l2w   = (const float*)d_in[14];
    const float* l2b   = (const float*)d_in[15];
    float* out = (float*)d_out;

    char* ws = (char*)d_ws;
    size_t off = 0;
    auto alloc = [&](size_t bytes) -> void* {
        void* p = ws + off;
        off += (bytes + 255) & ~(size_t)255;
        return p;
    };
    int* bucket_fill  = (int*)alloc((size_t)NB * 4);
    int* bucket_base  = (int*)alloc((size_t)NB * 4);
    int* row_ptr      = (int*)alloc((size_t)(N_NODES + 1) * 4);
    int* csr          = (int*)alloc((size_t)N_EDGES * 4);
    unsigned short* hb1 = (unsigned short*)alloc((size_t)N_NODES * HID * 2);
    unsigned char*  zb8 = (unsigned char*)alloc((size_t)N_NODES * HID);
    unsigned char*  h8  = (unsigned char*)alloc((size_t)N_NODES * HID);
    unsigned short* w1t = (unsigned short*)alloc(3 * 128 * 128 * 2);
    unsigned short* w2t = (unsigned short*)alloc(3 * 128 * 128 * 2);

    // staged (NB*CAP*4 = 25.22 MB) aliases hb1 (25.6 MB): hb1 is first written
    // by layer-2 mlp, long after bucket_csr consumes staged.
    unsigned* staged = (unsigned*)hb1;

    const int* srcA = ei;
    const int* dstA = ei + N_EDGES;

    // prep first: also initializes bucket_fill for the CSR build
    prep_kernel<<<(N_NODES * HID / 4 + 6 * 16384 + 255) / 256, 256, 0, stream>>>(
        x, h8, W1, W2, w1t, w2t, bucket_fill);
    bucket_place_kernel<<<NBLK_E, 256, 0, stream>>>(srcA, dstA, bucket_fill, staged);
    bucket_scan_kernel<<<1, 512, 0, stream>>>(bucket_fill, bucket_base);
    bucket_csr_kernel<<<NB, 256, 0, stream>>>(staged, bucket_fill, bucket_base, row_ptr, csr);

    for (int l = 0; l < 3; l++) {
        agg_kernel<<<N_NODES / 4, 256, 0, stream>>>(h8, row_ptr, csr, eps + l, zb8);
        mlp_kernel<<<(N_NODES + 63) / 64, 256, 0, stream>>>(
            zb8, w1t + l * 16384, b1 + l * 128, w2t + l * 16384, b2 + l * 128,
            gamma + l * 128, beta + l * 128, mu + l * 128, var + l * 128,
            (l == 2) ? hb1 : (unsigned short*)nullptr,
            (l == 2) ? (unsigned char*)nullptr : h8);
    }
    head_kernel<<<N_GRAPHS, 256, 0, stream>>>(hb1, batch, l1w, l1b, l2w, l2b, out);
}